// Round 1
// baseline (991.831 us; speedup 1.0000x reference)
//
#include <hip/hip_runtime.h>

// ---------------------------------------------------------------------------
// GQA attention block: QKV proj -> RoPE -> causal GQA flash attention -> out proj
// B=2 S=2048 D=4096 NH=32 NKV=8 HD=128 (QKV_DIM=6144)
// All heavy math in bf16 MFMA (16x16x32), fp32 accumulate/softmax.
// ---------------------------------------------------------------------------

typedef __bf16 bf16;
typedef bf16 bf16x8 __attribute__((ext_vector_type(8)));
typedef bf16 bf16x4 __attribute__((ext_vector_type(4)));
typedef float f32x4 __attribute__((ext_vector_type(4)));

#define B_ 2
#define S_ 2048
#define DM 4096
#define NH 32
#define NKV 8
#define HD 128
#define QKV_DIM 6144

// ---------------- cast fp32 -> bf16 (hidden states) ----------------
__global__ __launch_bounds__(256) void cast_f32_bf16(const float* __restrict__ src,
                                                     bf16* __restrict__ dst, int n) {
  int i = (blockIdx.x * 256 + threadIdx.x) * 4;
  float4 v = *(const float4*)(src + i);
  bf16x4 o;
  o[0] = (bf16)v.x; o[1] = (bf16)v.y; o[2] = (bf16)v.z; o[3] = (bf16)v.w;
  *(bf16x4*)(dst + i) = o;
}

// ---------------- transpose + cast weights: W[K][N] f32 -> Wt[N][K] bf16 ----
__global__ __launch_bounds__(256) void transpose_cast_w(const float* __restrict__ W,
                                                        bf16* __restrict__ Wt,
                                                        int K, int N) {
  __shared__ float tile[64][65];
  const int n0 = blockIdx.x * 64, k0 = blockIdx.y * 64;
  const int t = threadIdx.x, j = t & 63, i0 = t >> 6;
  for (int p = 0; p < 16; ++p) {
    int i = i0 + p * 4;
    tile[i][j] = W[(size_t)(k0 + i) * N + n0 + j];
  }
  __syncthreads();
  for (int p = 0; p < 16; ++p) {
    int n = i0 + p * 4;
    Wt[(size_t)(n0 + n) * K + k0 + j] = (bf16)tile[j][n];
  }
}

// ---------------- transpose V out of qkv: v_t[b][kv][d][s] ----------------
__global__ __launch_bounds__(256) void transpose_v(const bf16* __restrict__ qkv,
                                                   bf16* __restrict__ v_t) {
  __shared__ bf16 tile[64][65];
  const int s0 = blockIdx.x * 64;
  const int d0 = blockIdx.y * 64;
  const int bk = blockIdx.z;            // b*8+kv
  const int b = bk >> 3, kv = bk & 7;
  const int t = threadIdx.x, j = t & 63, i0 = t >> 6;
  const bf16* src = qkv + (size_t)b * S_ * QKV_DIM + 5120 + kv * HD;  // v offset 5120
  for (int p = 0; p < 16; ++p) {
    int i = i0 + p * 4;
    tile[i][j] = src[(size_t)(s0 + i) * QKV_DIM + d0 + j];
  }
  __syncthreads();
  bf16* dst = v_t + ((size_t)bk * HD + d0) * S_ + s0;
  for (int p = 0; p < 16; ++p) {
    int dd = i0 + p * 4;
    dst[(size_t)dd * S_ + j] = tile[j][dd];
  }
}

// ---------------- RoPE + repack q,k (q pre-scaled by 1/sqrt(HD)) ----------
__global__ __launch_bounds__(128) void rope_kernel(const bf16* __restrict__ qkv,
                                                   const float* __restrict__ cosT,
                                                   const float* __restrict__ sinT,
                                                   bf16* __restrict__ q_r,
                                                   bf16* __restrict__ k_r) {
  const int bs = blockIdx.x;            // b*S + s
  const int b = bs >> 11, s = bs & 2047;
  const int d = threadIdx.x;            // 0..127
  const float cv = cosT[s * HD + d];
  const float sv = sinT[s * HD + d];
  const bf16* row = qkv + (size_t)bs * QKV_DIM;
  const float scale = 0.08838834764831845f;  // 1/sqrt(128)
  for (int h = 0; h < NH; ++h) {
    float x = (float)row[h * HD + d];
    float xr = (d < 64) ? -(float)row[h * HD + d + 64] : (float)row[h * HD + d - 64];
    q_r[(((size_t)(b * NH + h)) * S_ + s) * HD + d] = (bf16)((x * cv + xr * sv) * scale);
  }
  for (int kv = 0; kv < NKV; ++kv) {
    float x = (float)row[DM + kv * HD + d];
    float xr = (d < 64) ? -(float)row[DM + kv * HD + d + 64] : (float)row[DM + kv * HD + d - 64];
    k_r[(((size_t)(b * NKV + kv)) * S_ + s) * HD + d] = (bf16)(x * cv + xr * sv);
  }
}

// ---------------- GEMM: C[M][N] = A[M][K] * Bt[N][K]^T (bf16, f32 acc) -----
// 128x128 tile, BK=32, 4 waves (2x2), each wave 64x64 = 4x4 mfma_16x16x32 tiles.
template <bool OUT_BF16>
__global__ __launch_bounds__(256) void gemm_bt(const bf16* __restrict__ A,
                                               const bf16* __restrict__ Bt,
                                               void* __restrict__ Cout,
                                               int M, int N, int K) {
  __shared__ bf16 As[128 * 40];   // +8 pad: b128 frag reads ~conflict-free
  __shared__ bf16 Bs[128 * 40];
  const int m0 = blockIdx.y * 128, n0 = blockIdx.x * 128;
  const int t = threadIdx.x;
  const int lane = t & 63, w = t >> 6;
  const int wm = (w >> 1) * 64, wn = (w & 1) * 64;
  const int quad = lane >> 4, c = lane & 15;

  f32x4 acc[4][4] = {};

  const int srow = t >> 1, scol = (t & 1) * 16;
  const bf16* Aptr = A + (size_t)(m0 + srow) * K + scol;
  const bf16* Bptr = Bt + (size_t)(n0 + srow) * K + scol;
  bf16* Asw = As + srow * 40 + scol;
  bf16* Bsw = Bs + srow * 40 + scol;

  for (int k0 = 0; k0 < K; k0 += 32) {
    bf16x8 a0 = *(const bf16x8*)(Aptr);
    bf16x8 a1 = *(const bf16x8*)(Aptr + 8);
    bf16x8 b0 = *(const bf16x8*)(Bptr);
    bf16x8 b1 = *(const bf16x8*)(Bptr + 8);
    Aptr += 32; Bptr += 32;
    __syncthreads();
    *(bf16x8*)(Asw) = a0;
    *(bf16x8*)(Asw + 8) = a1;
    *(bf16x8*)(Bsw) = b0;
    *(bf16x8*)(Bsw + 8) = b1;
    __syncthreads();
    bf16x8 af[4], bfr[4];
#pragma unroll
    for (int i = 0; i < 4; ++i)
      af[i] = *(const bf16x8*)(As + (wm + i * 16 + c) * 40 + quad * 8);
#pragma unroll
    for (int j = 0; j < 4; ++j)
      bfr[j] = *(const bf16x8*)(Bs + (wn + j * 16 + c) * 40 + quad * 8);
#pragma unroll
    for (int i = 0; i < 4; ++i)
#pragma unroll
      for (int j = 0; j < 4; ++j)
        acc[i][j] = __builtin_amdgcn_mfma_f32_16x16x32_bf16(af[i], bfr[j], acc[i][j], 0, 0, 0);
  }

#pragma unroll
  for (int i = 0; i < 4; ++i)
#pragma unroll
    for (int j = 0; j < 4; ++j) {
      const int row = m0 + wm + i * 16 + quad * 4;
      const int col = n0 + wn + j * 16 + c;
      if constexpr (OUT_BF16) {
        bf16* Cp = (bf16*)Cout;
#pragma unroll
        for (int r = 0; r < 4; ++r) Cp[(size_t)(row + r) * N + col] = (bf16)acc[i][j][r];
      } else {
        float* Cp = (float*)Cout;
#pragma unroll
        for (int r = 0; r < 4; ++r) Cp[(size_t)(row + r) * N + col] = acc[i][j][r];
      }
    }
}

// ---------------- flash attention (causal GQA) -----------------------------
// grid: (B*NH, S/64). 4 waves/block, wave w owns q rows [q0+16w, q0+16w+16).
// K-chunk = 32 keys. Ks[key][d] (+8 pad), Vs[d][key] (+8 pad), per-wave Ps.
#define SKS 136
#define SVS 40
#define SPS 40
__global__ __launch_bounds__(256) void attn_kernel(const bf16* __restrict__ q_r,
                                                   const bf16* __restrict__ k_r,
                                                   const bf16* __restrict__ v_t,
                                                   bf16* __restrict__ attn_out) {
  __shared__ bf16 Ks[32 * SKS];
  __shared__ bf16 Vs[128 * SVS];
  __shared__ bf16 Ps[4 * 16 * SPS];

  const int bh = blockIdx.x;           // b*NH + h
  const int b = bh >> 5, h = bh & 31;
  const int kv = h >> 2;               // N_GROUPS = 4
  const int q0 = blockIdx.y * 64;
  const int t = threadIdx.x, w = t >> 6, lane = t & 63;
  const int quad = lane >> 4, c = lane & 15;

  // Q fragments (held in registers across the whole K loop)
  const bf16* qrow = q_r + ((size_t)(b * NH + h) * S_ + (q0 + w * 16 + c)) * HD;
  bf16x8 qf[4];
#pragma unroll
  for (int kk = 0; kk < 4; ++kk) qf[kk] = *(const bf16x8*)(qrow + quad * 8 + kk * 32);

  float m_i[4], l_i[4];
  f32x4 o_acc[8];
#pragma unroll
  for (int r = 0; r < 4; ++r) { m_i[r] = -1e30f; l_i[r] = 0.f; }
#pragma unroll
  for (int n = 0; n < 8; ++n) o_acc[n] = (f32x4){0.f, 0.f, 0.f, 0.f};

  const bf16* kb_ptr = k_r + (size_t)(b * NKV + kv) * S_ * HD;
  const bf16* vb_ptr = v_t + (size_t)(b * NKV + kv) * HD * S_;
  bf16* Psw = Ps + w * 16 * SPS;

  const int nch = (q0 + 64) >> 5;
  const int ks_key = t >> 3, ks_doff = (t & 7) * 16;
  const int vs_d = t >> 1, vs_koff = (t & 1) * 16;

  for (int ch = 0; ch < nch; ++ch) {
    const int kb = ch * 32;
    __syncthreads();   // previous chunk's LDS reads done before overwrite
    {
      const bf16* kp = kb_ptr + (size_t)(kb + ks_key) * HD + ks_doff;
      bf16x8 kv0 = *(const bf16x8*)(kp);
      bf16x8 kv1 = *(const bf16x8*)(kp + 8);
      const bf16* vp = vb_ptr + (size_t)vs_d * S_ + kb + vs_koff;
      bf16x8 vv0 = *(const bf16x8*)(vp);
      bf16x8 vv1 = *(const bf16x8*)(vp + 8);
      *(bf16x8*)(Ks + ks_key * SKS + ks_doff) = kv0;
      *(bf16x8*)(Ks + ks_key * SKS + ks_doff + 8) = kv1;
      *(bf16x8*)(Vs + vs_d * SVS + vs_koff) = vv0;
      *(bf16x8*)(Vs + vs_d * SVS + vs_koff + 8) = vv1;
    }
    __syncthreads();

    // S = Q K^T  (scale pre-applied to Q)
    f32x4 s0 = (f32x4){0.f, 0.f, 0.f, 0.f};
    f32x4 s1 = (f32x4){0.f, 0.f, 0.f, 0.f};
#pragma unroll
    for (int kk = 0; kk < 4; ++kk) {
      bf16x8 kf0 = *(const bf16x8*)(Ks + c * SKS + quad * 8 + kk * 32);
      bf16x8 kf1 = *(const bf16x8*)(Ks + (16 + c) * SKS + quad * 8 + kk * 32);
      s0 = __builtin_amdgcn_mfma_f32_16x16x32_bf16(qf[kk], kf0, s0, 0, 0, 0);
      s1 = __builtin_amdgcn_mfma_f32_16x16x32_bf16(qf[kk], kf1, s1, 0, 0, 0);
    }

    // online softmax (rows quad*4+r; 16-lane quad-group reductions)
    float alpha[4];
#pragma unroll
    for (int r = 0; r < 4; ++r) {
      const int row = q0 + w * 16 + quad * 4 + r;
      float v0 = s0[r], v1 = s1[r];
      if (kb + c > row) v0 = -1e30f;
      if (kb + 16 + c > row) v1 = -1e30f;
      float mx = fmaxf(v0, v1);
#pragma unroll
      for (int off = 1; off < 16; off <<= 1) mx = fmaxf(mx, __shfl_xor(mx, off, 64));
      const float mnew = fmaxf(m_i[r], mx);
      const float p0 = __expf(v0 - mnew);
      const float p1 = __expf(v1 - mnew);
      float sum = p0 + p1;
#pragma unroll
      for (int off = 1; off < 16; off <<= 1) sum += __shfl_xor(sum, off, 64);
      alpha[r] = __expf(m_i[r] - mnew);
      m_i[r] = mnew;
      l_i[r] = l_i[r] * alpha[r] + sum;
      Psw[(quad * 4 + r) * SPS + c] = (bf16)p0;
      Psw[(quad * 4 + r) * SPS + 16 + c] = (bf16)p1;
    }

    // rescale O
#pragma unroll
    for (int n = 0; n < 8; ++n)
#pragma unroll
      for (int r = 0; r < 4; ++r) o_acc[n][r] *= alpha[r];

    __syncthreads();   // order Ps cross-lane writes before A-frag reads

    // O += P V
    bf16x8 pf = *(const bf16x8*)(Psw + c * SPS + quad * 8);
#pragma unroll
    for (int n = 0; n < 8; ++n) {
      bf16x8 vf = *(const bf16x8*)(Vs + (n * 16 + c) * SVS + quad * 8);
      o_acc[n] = __builtin_amdgcn_mfma_f32_16x16x32_bf16(pf, vf, o_acc[n], 0, 0, 0);
    }
  }

  // epilogue: O /= l, write attn_out[b][s][h*128+d]
#pragma unroll
  for (int n = 0; n < 8; ++n)
#pragma unroll
    for (int r = 0; r < 4; ++r) {
      const int row = q0 + w * 16 + quad * 4 + r;
      const float ov = o_acc[n][r] / l_i[r];
      attn_out[((size_t)b * S_ + row) * DM + h * HD + n * 16 + c] = (bf16)ov;
    }
}

// ---------------------------------------------------------------------------
extern "C" void kernel_launch(void* const* d_in, const int* in_sizes, int n_in,
                              void* d_out, int out_size, void* d_ws, size_t ws_size,
                              hipStream_t stream) {
  const float* hidden = (const float*)d_in[0];
  const float* cosT = (const float*)d_in[1];
  const float* sinT = (const float*)d_in[2];
  const float* Wqkv = (const float*)d_in[3];
  const float* Wout = (const float*)d_in[4];
  float* out = (float*)d_out;
  char* ws = (char*)d_ws;

  // workspace layout (regions reused once dead):
  //   [0, 50.3MB):   WqkvT (k2..k3)  -> q_r [0,33.5MB) + k_r [33.5,41.9MB) (k4+)
  //   [50.3, 83.9):  WoutT (k2..k7)
  //   [83.9, 117.4): h_bf16 (k1,k3)  -> attn_out (k6..k7)
  //   [117.4,125.8): v_t (k5..k6)
  // qkv (50.3MB bf16) lives in d_out (67.1MB), dead before final GEMM writes.
  bf16* WqkvT = (bf16*)(ws + 0);
  bf16* q_r = (bf16*)(ws + 0);
  bf16* k_r = (bf16*)(ws + 33554432);
  bf16* WoutT = (bf16*)(ws + 50331648);
  bf16* h_bf = (bf16*)(ws + 83886080);
  bf16* attn_out = (bf16*)(ws + 83886080);
  bf16* v_t = (bf16*)(ws + 117440512);
  bf16* qkv = (bf16*)d_out;

  // 1. cast hidden -> bf16
  cast_f32_bf16<<<dim3(16384), dim3(256), 0, stream>>>(hidden, h_bf, B_ * S_ * DM);
  // 2. transpose+cast weights
  transpose_cast_w<<<dim3(QKV_DIM / 64, DM / 64), dim3(256), 0, stream>>>(Wqkv, WqkvT, DM, QKV_DIM);
  transpose_cast_w<<<dim3(DM / 64, DM / 64), dim3(256), 0, stream>>>(Wout, WoutT, DM, DM);
  // 3. QKV projection (writes bf16 qkv into d_out region)
  gemm_bt<true><<<dim3(QKV_DIM / 128, (B_ * S_) / 128), dim3(256), 0, stream>>>(
      h_bf, WqkvT, (void*)qkv, B_ * S_, QKV_DIM, DM);
  // 4. RoPE + repack q,k
  rope_kernel<<<dim3(B_ * S_), dim3(128), 0, stream>>>(qkv, cosT, sinT, q_r, k_r);
  // 5. transpose V
  transpose_v<<<dim3(S_ / 64, HD / 64, B_ * NKV), dim3(256), 0, stream>>>(qkv, v_t);
  // 6. flash attention
  attn_kernel<<<dim3(B_ * NH, S_ / 64), dim3(256), 0, stream>>>(q_r, k_r, v_t, attn_out);
  // 7. output projection (fp32 out)
  gemm_bt<false><<<dim3(DM / 128, (B_ * S_) / 128), dim3(256), 0, stream>>>(
      attn_out, WoutT, (void*)out, B_ * S_, DM, DM);
}